// Round 11
// baseline (155.437 us; speedup 1.0000x reference)
//
#include <hip/hip_runtime.h>

// hd_id_lvl_decoder: scores[b,i,l] = sum_d x[b,d]*id[i,d]*lvl[l,d]; out[b,i] = argmax_l * 0.015625
// B=64, NUM_ID=256, NUM_LVL=64, D=10000.
//
// f16x2-split MFMA, 3-term (hh + hl + lh; ll dropped ~6e-6, below fp32 noise):
// Phase 0: split id_hvs into f16 hi/lo arrays (zero-padded K to 10016 = 313*32) in ws.
// Phase 1: R7 inner loop EXACTLY (it is the proven optimum: R8 global_load_lds, R9 global
//          gather, R10 manual vmcnt/prefetch all regressed). Occupancy change only:
//          SINGLE-buffered 32 KB LDS + 2-barrier chunk loop, S=16 -> grid 1024 = 4 blocks/CU
//          (vs R7's 2). Cross-block overlap covers staging (m114); scheduling left to compiler.
// Phase 2: one wave per (b,i), lane = l: fp64 sum of S partials, shfl_xor argmax (first ties).

typedef _Float16 f16x8 __attribute__((ext_vector_type(8)));
typedef float f32x4 __attribute__((ext_vector_type(4)));

constexpr int D    = 10000;
constexpr int KPAD = 10016;            // 313 * 32
constexpr int B    = 64;
constexpr int NI   = 256;
constexpr int NL   = 64;
constexpr int BK   = 32;
constexpr int NCH  = KPAD / BK;        // 313 chunks
constexpr int BM   = 128;              // i per block
constexpr float BIN_LEN = 0.015625f;

constexpr size_t IDSZ = (size_t)NI * KPAD;   // elements per id array

__device__ __forceinline__ float4 ld4(const float* p) {
    return *reinterpret_cast<const float4*>(p);
}

// ---------------- Phase 0: split id into f16 hi/lo, zero-pad to KPAD ----------------
__global__ __launch_bounds__(256)
void hd_split_id(const float* __restrict__ id_hvs,
                 _Float16* __restrict__ idh, _Float16* __restrict__ idl) {
    const int i = blockIdx.x;          // 256 blocks, one i-row each
    for (int k = threadIdx.x; k < KPAD; k += 256) {
        float v = (k < D) ? id_hvs[(size_t)i * D + k] : 0.0f;
        _Float16 h = (_Float16)v;
        _Float16 lo = (_Float16)(v - (float)h);
        idh[(size_t)i * KPAD + k] = h;
        idl[(size_t)i * KPAD + k] = lo;
    }
}

// ---------------- Phase 1: MFMA main kernel (single-buffered, 32 KB LDS) ----------------
__global__ __launch_bounds__(256)
void hd_mfma(const float* __restrict__ x, const float* __restrict__ lvl_hvs,
             const _Float16* __restrict__ idh, const _Float16* __restrict__ idl,
             float* __restrict__ part, int S) {
    // slot = kg ^ ((row>>1)&3) swizzle -> conflict-free (R6/R7 measured: 0)
    __shared__ f16x8 sA[2][BM][4];       // id tile  [hi/lo][row][slot], 16 KB
    __shared__ f16x8 sW[2][2][NL][4];    // w tile   [hi/lo][b][row][slot], 16 KB

    const int tid = threadIdx.x;
    const int bx  = blockIdx.x;
    const int s     = bx >> 6;          // 0..S-1
    const int ibase = (bx & 1) * BM;    // 0 or 128
    const int b0    = ((bx >> 1) & 31) * 2;

    // chunk range for this split
    const int cb = NCH / S, cr = NCH % S;
    const int cstart = s * cb + (s < cr ? s : cr);
    const int nch    = cb + (s < cr ? 1 : 0);

    // w staging: thread -> lvl row (tid>>2)&63, kg tid&3
    const int w_row = (tid >> 2) & 63, w_kg = tid & 3;
    const int w_slot = w_kg ^ ((w_row >> 1) & 3);

    // wave / fragment decode: 4 waves as 2(i) x 2(b)
    const int wid = tid >> 6;
    const int wm = wid >> 1, wn = wid & 1;          // rows [wm*64,+64), b = b0+wn
    const int lr = tid & 15, lq = (tid >> 4) & 3;   // lane row/col sel, k-group

    f32x4 accM[4][4], accC[4][4];
#pragma unroll
    for (int f = 0; f < 4; ++f)
#pragma unroll
        for (int g = 0; g < 4; ++g) {
            accM[f][g] = (f32x4)0.0f;
            accC[f][g] = (f32x4)0.0f;
        }

    f16x8 r_id[4];
    float r_lv[8], r_x0[8], r_x1[8];

    auto LOAD_A = [&](int c) {
        const int k0 = (cstart + c) * BK;
#pragma unroll
        for (int m = 0; m < 4; ++m) {
            int u = tid + 256 * m;
            int arr = u >> 9, u2 = u & 511;
            int row = u2 >> 2, kg = u2 & 3;
            const _Float16* src = (arr ? idl : idh)
                + (size_t)(ibase + row) * KPAD + k0 + kg * 8;
            r_id[m] = *reinterpret_cast<const f16x8*>(src);
        }
    };

    auto WRITE_A = [&]() {
#pragma unroll
        for (int m = 0; m < 4; ++m) {
            int u = tid + 256 * m;
            int arr = u >> 9, u2 = u & 511;
            int row = u2 >> 2, kg = u2 & 3;
            sA[arr][row][kg ^ ((row >> 1) & 3)] = r_id[m];
        }
    };

    auto LOAD_W = [&](int c) {
        const int k0 = (cstart + c) * BK;
        const int kb = k0 + w_kg * 8;
        const float* lp  = lvl_hvs + (size_t)w_row * D + kb;
        const float* xp0 = x + (size_t)b0 * D + kb;
        const float* xp1 = xp0 + D;
        if (kb + 8 <= D) {
            float4 a0 = ld4(lp),  a1 = ld4(lp + 4);
            float4 c0 = ld4(xp0), c1 = ld4(xp0 + 4);
            float4 d0 = ld4(xp1), d1 = ld4(xp1 + 4);
            r_lv[0] = a0.x; r_lv[1] = a0.y; r_lv[2] = a0.z; r_lv[3] = a0.w;
            r_lv[4] = a1.x; r_lv[5] = a1.y; r_lv[6] = a1.z; r_lv[7] = a1.w;
            r_x0[0] = c0.x; r_x0[1] = c0.y; r_x0[2] = c0.z; r_x0[3] = c0.w;
            r_x0[4] = c1.x; r_x0[5] = c1.y; r_x0[6] = c1.z; r_x0[7] = c1.w;
            r_x1[0] = d0.x; r_x1[1] = d0.y; r_x1[2] = d0.z; r_x1[3] = d0.w;
            r_x1[4] = d1.x; r_x1[5] = d1.y; r_x1[6] = d1.z; r_x1[7] = d1.w;
        } else {
#pragma unroll
            for (int e = 0; e < 8; ++e) {
                bool in = (kb + e) < D;
                r_lv[e] = in ? lp[e]  : 0.0f;
                r_x0[e] = in ? xp0[e] : 0.0f;
                r_x1[e] = in ? xp1[e] : 0.0f;
            }
        }
    };

    auto WRITE_W = [&]() {
#pragma unroll
        for (int bs = 0; bs < 2; ++bs) {
            const float* rx = bs ? r_x1 : r_x0;
            f16x8 h, lo;
#pragma unroll
            for (int e = 0; e < 8; ++e) {
                float w = rx[e] * r_lv[e];
                _Float16 hh = (_Float16)w;
                h[e] = hh;
                lo[e] = (_Float16)(w - (float)hh);
            }
            sW[0][bs][w_row][w_slot] = h;
            sW[1][bs][w_row][w_slot] = lo;
        }
    };

    auto COMPUTE = [&]() {
        f16x8 bh[4], bl[4];
#pragma unroll
        for (int g = 0; g < 4; ++g) {
            int col = g * 16 + lr;
            int slot = lq ^ ((col >> 1) & 3);
            bh[g] = sW[0][wn][col][slot];
            bl[g] = sW[1][wn][col][slot];
        }
#pragma unroll
        for (int f = 0; f < 4; ++f) {
            int row = wm * 64 + f * 16 + lr;
            int slot = lq ^ ((row >> 1) & 3);
            f16x8 ah = sA[0][row][slot];
            f16x8 al = sA[1][row][slot];
#pragma unroll
            for (int g = 0; g < 4; ++g) {
                accM[f][g] = __builtin_amdgcn_mfma_f32_16x16x32_f16(ah, bh[g], accM[f][g], 0, 0, 0);
                accC[f][g] = __builtin_amdgcn_mfma_f32_16x16x32_f16(ah, bl[g], accC[f][g], 0, 0, 0);
                accC[f][g] = __builtin_amdgcn_mfma_f32_16x16x32_f16(al, bh[g], accC[f][g], 0, 0, 0);
            }
        }
    };

    // prologue: chunk 0 staged
    LOAD_A(0);
    LOAD_W(0);
    WRITE_A();
    WRITE_W();
    __syncthreads();

    for (int c = 0; c < nch; ++c) {
        const bool more = (c + 1 < nch);
        if (more) { LOAD_A(c + 1); LOAD_W(c + 1); }   // global->reg, overlaps COMPUTE
        COMPUTE();
        __syncthreads();                // all waves done READING the single buffer
        if (more) { WRITE_A(); WRITE_W(); }
        __syncthreads();                // writes visible
    }

    // epilogue: D layout col(lane&15)=l, row(lq*4+reg)=i offset. main + corr in fp32.
    float* outp = part + (size_t)(s * B + b0 + wn) * NI * NL;
#pragma unroll
    for (int f = 0; f < 4; ++f) {
#pragma unroll
        for (int g = 0; g < 4; ++g) {
            const int i0 = ibase + wm * 64 + f * 16 + lq * 4;
            const int l  = g * 16 + lr;
#pragma unroll
            for (int r = 0; r < 4; ++r) {
                outp[(size_t)(i0 + r) * NL + l] = accM[f][g][r] + accC[f][g][r];
            }
        }
    }
}

// ---------------- Phase 2: fp64 combine + argmax (one wave per (b,i)) ----------------
__global__ __launch_bounds__(256)
void hd_phase2(const float* __restrict__ ws, float* __restrict__ out, int SS) {
    const int wid  = blockIdx.x * 4 + (threadIdx.x >> 6);   // (b,i) flat index
    const int lane = threadIdx.x & 63;                       // l
    const int b = wid >> 8, i = wid & 255;
    const float* p = ws + ((size_t)b * NI + i) * NL + lane;
    const size_t sstride = (size_t)B * NI * NL;              // 1,048,576

    double s0 = 0.0, s1 = 0.0, s2 = 0.0, s3 = 0.0;
    int ss = 0;
    for (; ss + 4 <= SS; ss += 4) {
        s0 += (double)p[(size_t)(ss + 0) * sstride];
        s1 += (double)p[(size_t)(ss + 1) * sstride];
        s2 += (double)p[(size_t)(ss + 2) * sstride];
        s3 += (double)p[(size_t)(ss + 3) * sstride];
    }
    for (; ss < SS; ++ss) s0 += (double)p[(size_t)ss * sstride];

    double mv = (s0 + s1) + (s2 + s3);
    int mi = lane;
#pragma unroll
    for (int off = 1; off < 64; off <<= 1) {
        double ov = __shfl_xor(mv, off);
        int   oi  = __shfl_xor(mi, off);
        if (ov > mv || (ov == mv && oi < mi)) { mv = ov; mi = oi; }  // first-index tie-break
    }
    if (lane == 0) out[wid] = (float)mi * BIN_LEN;
}

extern "C" void kernel_launch(void* const* d_in, const int* in_sizes, int n_in,
                              void* d_out, int out_size, void* d_ws, size_t ws_size,
                              hipStream_t stream) {
    const float* x       = (const float*)d_in[0];
    const float* id_hvs  = (const float*)d_in[1];
    const float* lvl_hvs = (const float*)d_in[2];
    float* out = (float*)d_out;

    // pick S (k-splits): need S*4MB partials + 10.25MB id arrays in ws
    int S = 16;
    while (S > 1 && ws_size < ((size_t)S << 22) + 2 * IDSZ * sizeof(_Float16)) S >>= 1;

    float*     part = (float*)d_ws;
    _Float16*  idh  = (_Float16*)((char*)d_ws + ((size_t)S << 22));
    _Float16*  idl  = idh + IDSZ;

    hd_split_id<<<dim3(NI), dim3(256), 0, stream>>>(id_hvs, idh, idl);
    // S*64 blocks: S x 32 b-pairs x 2 i-tiles (S=16 -> 1024 = 4 blocks/CU at 32 KB LDS)
    hd_mfma<<<dim3(S * 64), dim3(256), 0, stream>>>(x, lvl_hvs, idh, idl, part, S);
    hd_phase2<<<dim3(B * NI / 4), dim3(256), 0, stream>>>(part, out, S);
}

// Round 12
// 127.101 us; speedup vs baseline: 1.2229x; 1.2229x over previous
//
#include <hip/hip_runtime.h>

// hd_id_lvl_decoder: scores[b,i,l] = sum_d x[b,d]*id[i,d]*lvl[l,d]; out[b,i] = argmax_l * 0.015625
// B=64, NUM_ID=256, NUM_LVL=64, D=10000.
//
// f16x2-split MFMA, 3-term (hh + hl + lh) into a SINGLE accumulator (64 AGPR).
// Occupancy law (R7-R11 post-mortem): waves/SIMD = floor(512/(VGPR+AGPR)).
//   dual-acc (128 AGPR) capped everything at 2 waves/SIMD; VGPR>128 variants fell to 1.
// This round: acc merge (64 AGPR) + __launch_bounds__(256,3) (VGPR target <=106)
//   + LDS 48 KB (sA dbuf 32 + sW single 16) -> 3 blocks/CU, 12 waves/CU.
// S=16 k-splits keeps accumulation chains short (noise ~2.3e-4, = proven R7 level).
// Phase 2: one wave per (b,i), lane = l: fp64 sum of S partials, shfl_xor argmax (first ties).

typedef _Float16 f16x8 __attribute__((ext_vector_type(8)));
typedef float f32x4 __attribute__((ext_vector_type(4)));

constexpr int D    = 10000;
constexpr int KPAD = 10016;            // 313 * 32
constexpr int B    = 64;
constexpr int NI   = 256;
constexpr int NL   = 64;
constexpr int BK   = 32;
constexpr int NCH  = KPAD / BK;        // 313 chunks
constexpr int BM   = 128;              // i per block
constexpr float BIN_LEN = 0.015625f;

constexpr size_t IDSZ = (size_t)NI * KPAD;   // elements per id array

__device__ __forceinline__ float4 ld4(const float* p) {
    return *reinterpret_cast<const float4*>(p);
}

// ---------------- Phase 0: split id into f16 hi/lo, zero-pad to KPAD ----------------
__global__ __launch_bounds__(256)
void hd_split_id(const float* __restrict__ id_hvs,
                 _Float16* __restrict__ idh, _Float16* __restrict__ idl) {
    const int i = blockIdx.x;          // 256 blocks, one i-row each
    for (int k = threadIdx.x; k < KPAD; k += 256) {
        float v = (k < D) ? id_hvs[(size_t)i * D + k] : 0.0f;
        _Float16 h = (_Float16)v;
        _Float16 lo = (_Float16)(v - (float)h);
        idh[(size_t)i * KPAD + k] = h;
        idl[(size_t)i * KPAD + k] = lo;
    }
}

// ---------------- Phase 1: MFMA main kernel ----------------
__global__ __launch_bounds__(256, 3)
void hd_mfma(const float* __restrict__ x, const float* __restrict__ lvl_hvs,
             const _Float16* __restrict__ idh, const _Float16* __restrict__ idl,
             float* __restrict__ part, int S) {
    // slot = kg ^ ((row>>1)&3) swizzle -> conflict-free (R6/R7 measured: 0)
    __shared__ f16x8 sA[2][2][BM][4];    // id tiles [buf][hi/lo][row][slot], 32 KB (dbuf)
    __shared__ f16x8 sW[2][2][NL][4];    // w tile   [hi/lo][b][row][slot], 16 KB (single)

    const int tid = threadIdx.x;
    const int bx  = blockIdx.x;
    const int s     = bx >> 6;          // 0..S-1
    const int ibase = (bx & 1) * BM;    // 0 or 128
    const int b0    = ((bx >> 1) & 31) * 2;

    // chunk range for this split
    const int cb = NCH / S, cr = NCH % S;
    const int cstart = s * cb + (s < cr ? s : cr);
    const int nch    = cb + (s < cr ? 1 : 0);

    // w staging: thread -> lvl row (tid>>2)&63, kg tid&3
    const int w_row = (tid >> 2) & 63, w_kg = tid & 3;
    const int w_slot = w_kg ^ ((w_row >> 1) & 3);

    // wave / fragment decode: 4 waves as 2(i) x 2(b)
    const int wid = tid >> 6;
    const int wm = wid >> 1, wn = wid & 1;          // rows [wm*64,+64), b = b0+wn
    const int lr = tid & 15, lq = (tid >> 4) & 3;   // lane row/col sel, k-group

    f32x4 acc[4][4];                   // single accumulator: 64 AGPR
#pragma unroll
    for (int f = 0; f < 4; ++f)
#pragma unroll
        for (int g = 0; g < 4; ++g) acc[f][g] = (f32x4)0.0f;

    f16x8 r_id[4];
    float r_lv[8], r_x0[8], r_x1[8];

    auto LOAD_A = [&](int c) {
        const int k0 = (cstart + c) * BK;
#pragma unroll
        for (int m = 0; m < 4; ++m) {
            int u = tid + 256 * m;
            int arr = u >> 9, u2 = u & 511;
            int row = u2 >> 2, kg = u2 & 3;
            const _Float16* src = (arr ? idl : idh)
                + (size_t)(ibase + row) * KPAD + k0 + kg * 8;
            r_id[m] = *reinterpret_cast<const f16x8*>(src);
        }
    };

    auto WRITE_A = [&](int buf) {
#pragma unroll
        for (int m = 0; m < 4; ++m) {
            int u = tid + 256 * m;
            int arr = u >> 9, u2 = u & 511;
            int row = u2 >> 2, kg = u2 & 3;
            sA[buf][arr][row][kg ^ ((row >> 1) & 3)] = r_id[m];
        }
    };

    auto LOAD_W = [&](int c) {
        const int k0 = (cstart + c) * BK;
        const int kb = k0 + w_kg * 8;
        const float* lp  = lvl_hvs + (size_t)w_row * D + kb;
        const float* xp0 = x + (size_t)b0 * D + kb;
        const float* xp1 = xp0 + D;
        if (kb + 8 <= D) {
            float4 a0 = ld4(lp),  a1 = ld4(lp + 4);
            float4 c0 = ld4(xp0), c1 = ld4(xp0 + 4);
            float4 d0 = ld4(xp1), d1 = ld4(xp1 + 4);
            r_lv[0] = a0.x; r_lv[1] = a0.y; r_lv[2] = a0.z; r_lv[3] = a0.w;
            r_lv[4] = a1.x; r_lv[5] = a1.y; r_lv[6] = a1.z; r_lv[7] = a1.w;
            r_x0[0] = c0.x; r_x0[1] = c0.y; r_x0[2] = c0.z; r_x0[3] = c0.w;
            r_x0[4] = c1.x; r_x0[5] = c1.y; r_x0[6] = c1.z; r_x0[7] = c1.w;
            r_x1[0] = d0.x; r_x1[1] = d0.y; r_x1[2] = d0.z; r_x1[3] = d0.w;
            r_x1[4] = d1.x; r_x1[5] = d1.y; r_x1[6] = d1.z; r_x1[7] = d1.w;
        } else {
#pragma unroll
            for (int e = 0; e < 8; ++e) {
                bool in = (kb + e) < D;
                r_lv[e] = in ? lp[e]  : 0.0f;
                r_x0[e] = in ? xp0[e] : 0.0f;
                r_x1[e] = in ? xp1[e] : 0.0f;
            }
        }
    };

    auto WRITE_W = [&]() {
#pragma unroll
        for (int bs = 0; bs < 2; ++bs) {
            const float* rx = bs ? r_x1 : r_x0;
            f16x8 h, lo;
#pragma unroll
            for (int e = 0; e < 8; ++e) {
                float w = rx[e] * r_lv[e];
                _Float16 hh = (_Float16)w;
                h[e] = hh;
                lo[e] = (_Float16)(w - (float)hh);
            }
            sW[0][bs][w_row][w_slot] = h;
            sW[1][bs][w_row][w_slot] = lo;
        }
    };

    auto COMPUTE = [&](int buf) {
        f16x8 bh[4], bl[4];
#pragma unroll
        for (int g = 0; g < 4; ++g) {
            int col = g * 16 + lr;
            int slot = lq ^ ((col >> 1) & 3);
            bh[g] = sW[0][wn][col][slot];
            bl[g] = sW[1][wn][col][slot];
        }
#pragma unroll
        for (int f = 0; f < 4; ++f) {
            int row = wm * 64 + f * 16 + lr;
            int slot = lq ^ ((row >> 1) & 3);
            f16x8 ah = sA[buf][0][row][slot];
            f16x8 al = sA[buf][1][row][slot];
#pragma unroll
            for (int g = 0; g < 4; ++g) {
                acc[f][g] = __builtin_amdgcn_mfma_f32_16x16x32_f16(ah, bh[g], acc[f][g], 0, 0, 0);
                acc[f][g] = __builtin_amdgcn_mfma_f32_16x16x32_f16(ah, bl[g], acc[f][g], 0, 0, 0);
                acc[f][g] = __builtin_amdgcn_mfma_f32_16x16x32_f16(al, bh[g], acc[f][g], 0, 0, 0);
            }
        }
    };

    // prologue: chunk 0 staged (sA buf0 + sW)
    LOAD_A(0);
    LOAD_W(0);
    WRITE_A(0);
    WRITE_W();
    __syncthreads();

    int cur = 0;
    for (int c = 0; c < nch; ++c) {
        const bool more = (c + 1 < nch);
        if (more) { LOAD_A(c + 1); LOAD_W(c + 1); }   // global->reg, overlaps COMPUTE
        COMPUTE(cur);
        if (more) WRITE_A(cur ^ 1);     // other sA buffer: safe before barrier
        __syncthreads();                // all waves done reading sW(c) [and sA writes issued]
        if (more) WRITE_W();            // overwrite single sW buffer
        __syncthreads();                // sW(c+1) + sA[cur^1] visible
        cur ^= 1;
    }

    // epilogue: D layout col(lane&15)=l, row(lq*4+reg)=i offset.
    float* outp = part + (size_t)(s * B + b0 + wn) * NI * NL;
#pragma unroll
    for (int f = 0; f < 4; ++f) {
#pragma unroll
        for (int g = 0; g < 4; ++g) {
            const int i0 = ibase + wm * 64 + f * 16 + lq * 4;
            const int l  = g * 16 + lr;
#pragma unroll
            for (int r = 0; r < 4; ++r) {
                outp[(size_t)(i0 + r) * NL + l] = acc[f][g][r];
            }
        }
    }
}

// ---------------- Phase 2: fp64 combine + argmax (one wave per (b,i)) ----------------
__global__ __launch_bounds__(256)
void hd_phase2(const float* __restrict__ ws, float* __restrict__ out, int SS) {
    const int wid  = blockIdx.x * 4 + (threadIdx.x >> 6);   // (b,i) flat index
    const int lane = threadIdx.x & 63;                       // l
    const int b = wid >> 8, i = wid & 255;
    const float* p = ws + ((size_t)b * NI + i) * NL + lane;
    const size_t sstride = (size_t)B * NI * NL;              // 1,048,576

    double s0 = 0.0, s1 = 0.0, s2 = 0.0, s3 = 0.0;
    int ss = 0;
    for (; ss + 4 <= SS; ss += 4) {
        s0 += (double)p[(size_t)(ss + 0) * sstride];
        s1 += (double)p[(size_t)(ss + 1) * sstride];
        s2 += (double)p[(size_t)(ss + 2) * sstride];
        s3 += (double)p[(size_t)(ss + 3) * sstride];
    }
    for (; ss < SS; ++ss) s0 += (double)p[(size_t)ss * sstride];

    double mv = (s0 + s1) + (s2 + s3);
    int mi = lane;
#pragma unroll
    for (int off = 1; off < 64; off <<= 1) {
        double ov = __shfl_xor(mv, off);
        int   oi  = __shfl_xor(mi, off);
        if (ov > mv || (ov == mv && oi < mi)) { mv = ov; mi = oi; }  // first-index tie-break
    }
    if (lane == 0) out[wid] = (float)mi * BIN_LEN;
}

extern "C" void kernel_launch(void* const* d_in, const int* in_sizes, int n_in,
                              void* d_out, int out_size, void* d_ws, size_t ws_size,
                              hipStream_t stream) {
    const float* x       = (const float*)d_in[0];
    const float* id_hvs  = (const float*)d_in[1];
    const float* lvl_hvs = (const float*)d_in[2];
    float* out = (float*)d_out;

    // pick S (k-splits): need S*4MB partials + 10.3MB id arrays in ws
    int S = 16;
    while (S > 1 && ws_size < ((size_t)S << 22) + 2 * IDSZ * sizeof(_Float16)) S >>= 1;

    float*     part = (float*)d_ws;
    _Float16*  idh  = (_Float16*)((char*)d_ws + ((size_t)S << 22));
    _Float16*  idl  = idh + IDSZ;

    hd_split_id<<<dim3(NI), dim3(256), 0, stream>>>(id_hvs, idh, idl);
    // S*64 blocks: S x 32 b-pairs x 2 i-tiles (S=16 -> 1024 blocks)
    hd_mfma<<<dim3(S * 64), dim3(256), 0, stream>>>(x, lvl_hvs, idh, idl, part, S);
    hd_phase2<<<dim3(B * NI / 4), dim3(256), 0, stream>>>(part, out, S);
}

// Round 13
// 116.451 us; speedup vs baseline: 1.3348x; 1.0914x over previous
//
#include <hip/hip_runtime.h>

// hd_id_lvl_decoder: scores[b,i,l] = sum_d x[b,d]*id[i,d]*lvl[l,d]; out[b,i] = argmax_l * 0.015625
// B=64, NUM_ID=256, NUM_LVL=64, D=10000.
//
// f16x2-split MFMA, 3-term (hh+hl+lh) chained into a single acc (R12: absmax 0).
// R13: R7's proven ONE-barrier dbuf loop (R8-R12: every schedule edit regressed), but wave
// tile 128x64 (f=8): block = 256 i x 64 l x 2 b, 4 waves. LDS:MFMA instr ratio 0.375 vs 0.5,
// per-chunk compute 2x vs same barrier cost. acc = 128 AGPR single; launch_bounds(256,2)
// pins VGPR+AGPR <= 256 (2 waves/SIMD). LDS 80 KB -> 2 blocks/CU; grid 512 = full residency.
// Phase 2: one wave per (b,i), lane = l: fp64 sum of S partials, shfl_xor argmax (first ties).

typedef _Float16 f16x8 __attribute__((ext_vector_type(8)));
typedef float f32x4 __attribute__((ext_vector_type(4)));

constexpr int D    = 10000;
constexpr int KPAD = 10016;            // 313 * 32
constexpr int B    = 64;
constexpr int NI   = 256;
constexpr int NL   = 64;
constexpr int BK   = 32;
constexpr int NCH  = KPAD / BK;        // 313 chunks
constexpr float BIN_LEN = 0.015625f;

constexpr size_t IDSZ = (size_t)NI * KPAD;   // elements per id array

__device__ __forceinline__ float4 ld4(const float* p) {
    return *reinterpret_cast<const float4*>(p);
}

// ---------------- Phase 0: split id into f16 hi/lo, zero-pad to KPAD ----------------
__global__ __launch_bounds__(256)
void hd_split_id(const float* __restrict__ id_hvs,
                 _Float16* __restrict__ idh, _Float16* __restrict__ idl) {
    const int i = blockIdx.x;          // 256 blocks, one i-row each
    for (int k = threadIdx.x; k < KPAD; k += 256) {
        float v = (k < D) ? id_hvs[(size_t)i * D + k] : 0.0f;
        _Float16 h = (_Float16)v;
        _Float16 lo = (_Float16)(v - (float)h);
        idh[(size_t)i * KPAD + k] = h;
        idl[(size_t)i * KPAD + k] = lo;
    }
}

// ---------------- Phase 1: MFMA main kernel ----------------
__global__ __launch_bounds__(256, 2)
void hd_mfma(const float* __restrict__ x, const float* __restrict__ lvl_hvs,
             const _Float16* __restrict__ idh, const _Float16* __restrict__ idl,
             float* __restrict__ part, int S) {
    // slot = kg ^ ((row>>1)&3) swizzle -> conflict-free (R6/R7 measured: 0)
    __shared__ f16x8 sA[2][2][NI][4];    // id tiles [buf][hi/lo][row 0..255][slot], 64 KB
    __shared__ f16x8 sW[2][2][2][NL][4]; // w tiles  [buf][hi/lo][b][row][slot], 16 KB

    const int tid = threadIdx.x;
    const int bx  = blockIdx.x;
    const int s  = bx >> 5;             // 0..S-1
    const int b0 = (bx & 31) * 2;

    // chunk range for this split
    const int cb = NCH / S, cr = NCH % S;
    const int cstart = s * cb + (s < cr ? s : cr);
    const int nch    = cb + (s < cr ? 1 : 0);

    // w staging: thread -> lvl row (tid>>2)&63, kg tid&3 (both b's)
    const int w_row = (tid >> 2) & 63, w_kg = tid & 3;
    const int w_slot = w_kg ^ ((w_row >> 1) & 3);

    // wave / fragment decode: 4 waves as 2(i-half) x 2(b); wave tile 128i x 64l
    const int wid = tid >> 6;
    const int wm = wid >> 1, wn = wid & 1;          // rows [wm*128,+128), b = b0+wn
    const int lr = tid & 15, lq = (tid >> 4) & 3;   // lane row/col sel, k-group

    f32x4 acc[8][4];                    // 128 AGPR single accumulator
#pragma unroll
    for (int f = 0; f < 8; ++f)
#pragma unroll
        for (int g = 0; g < 4; ++g) acc[f][g] = (f32x4)0.0f;

    f16x8 r_id[8];                      // id staging: 8 f16x8 per thread per chunk
    float r_lv[8], r_x0[8], r_x1[8];

    auto LOAD_A = [&](int c) {
        const int k0 = (cstart + c) * BK;
#pragma unroll
        for (int m = 0; m < 8; ++m) {
            int u = tid + 256 * m;                  // 0..2047
            int arr = u >> 10, u2 = u & 1023;
            int row = u2 >> 2, kg = u2 & 3;
            const _Float16* src = (arr ? idl : idh)
                + (size_t)row * KPAD + k0 + kg * 8;
            r_id[m] = *reinterpret_cast<const f16x8*>(src);
        }
    };

    auto WRITE_A = [&](int buf) {
#pragma unroll
        for (int m = 0; m < 8; ++m) {
            int u = tid + 256 * m;
            int arr = u >> 10, u2 = u & 1023;
            int row = u2 >> 2, kg = u2 & 3;
            sA[buf][arr][row][kg ^ ((row >> 1) & 3)] = r_id[m];
        }
    };

    auto LOAD_W = [&](int c) {
        const int kb = (cstart + c) * BK + w_kg * 8;
        const float* lp  = lvl_hvs + (size_t)w_row * D + kb;
        const float* xp0 = x + (size_t)b0 * D + kb;
        const float* xp1 = xp0 + D;
        if (kb + 8 <= D) {
            float4 a0 = ld4(lp),  a1 = ld4(lp + 4);
            float4 c0 = ld4(xp0), c1 = ld4(xp0 + 4);
            float4 d0 = ld4(xp1), d1 = ld4(xp1 + 4);
            r_lv[0] = a0.x; r_lv[1] = a0.y; r_lv[2] = a0.z; r_lv[3] = a0.w;
            r_lv[4] = a1.x; r_lv[5] = a1.y; r_lv[6] = a1.z; r_lv[7] = a1.w;
            r_x0[0] = c0.x; r_x0[1] = c0.y; r_x0[2] = c0.z; r_x0[3] = c0.w;
            r_x0[4] = c1.x; r_x0[5] = c1.y; r_x0[6] = c1.z; r_x0[7] = c1.w;
            r_x1[0] = d0.x; r_x1[1] = d0.y; r_x1[2] = d0.z; r_x1[3] = d0.w;
            r_x1[4] = d1.x; r_x1[5] = d1.y; r_x1[6] = d1.z; r_x1[7] = d1.w;
        } else {
#pragma unroll
            for (int e = 0; e < 8; ++e) {
                bool in = (kb + e) < D;
                r_lv[e] = in ? lp[e]  : 0.0f;
                r_x0[e] = in ? xp0[e] : 0.0f;
                r_x1[e] = in ? xp1[e] : 0.0f;
            }
        }
    };

    auto WRITE_W = [&](int buf) {
#pragma unroll
        for (int bs = 0; bs < 2; ++bs) {
            const float* rx = bs ? r_x1 : r_x0;
            f16x8 h, lo;
#pragma unroll
            for (int e = 0; e < 8; ++e) {
                float w = rx[e] * r_lv[e];
                _Float16 hh = (_Float16)w;
                h[e] = hh;
                lo[e] = (_Float16)(w - (float)hh);
            }
            sW[buf][0][bs][w_row][w_slot] = h;
            sW[buf][1][bs][w_row][w_slot] = lo;
        }
    };

    auto COMPUTE = [&](int buf) {
        f16x8 bh[4], bl[4];
#pragma unroll
        for (int g = 0; g < 4; ++g) {
            int col = g * 16 + lr;
            int slot = lq ^ ((col >> 1) & 3);
            bh[g] = sW[buf][0][wn][col][slot];
            bl[g] = sW[buf][1][wn][col][slot];
        }
#pragma unroll
        for (int f = 0; f < 8; ++f) {
            int row = wm * 128 + f * 16 + lr;
            int slot = lq ^ ((row >> 1) & 3);
            f16x8 ah = sA[buf][0][row][slot];
            f16x8 al = sA[buf][1][row][slot];
#pragma unroll
            for (int g = 0; g < 4; ++g) {
                acc[f][g] = __builtin_amdgcn_mfma_f32_16x16x32_f16(ah, bh[g], acc[f][g], 0, 0, 0);
                acc[f][g] = __builtin_amdgcn_mfma_f32_16x16x32_f16(ah, bl[g], acc[f][g], 0, 0, 0);
                acc[f][g] = __builtin_amdgcn_mfma_f32_16x16x32_f16(al, bh[g], acc[f][g], 0, 0, 0);
            }
        }
    };

    // prologue: chunk 0 staged into buf 0
    LOAD_A(0);
    LOAD_W(0);
    WRITE_A(0);
    WRITE_W(0);
    __syncthreads();

    int cur = 0;
    for (int c = 0; c < nch; ++c) {
        const bool more = (c + 1 < nch);
        if (more) { LOAD_A(c + 1); LOAD_W(c + 1); }   // global->reg, overlaps COMPUTE
        COMPUTE(cur);
        if (more) { WRITE_A(cur ^ 1); WRITE_W(cur ^ 1); }
        __syncthreads();
        cur ^= 1;
    }

    // epilogue: D layout col(lane&15)=l, row(lq*4+reg)=i offset.
    float* outp = part + (size_t)(s * B + b0 + wn) * NI * NL;
#pragma unroll
    for (int f = 0; f < 8; ++f) {
#pragma unroll
        for (int g = 0; g < 4; ++g) {
            const int i0 = wm * 128 + f * 16 + lq * 4;
            const int l  = g * 16 + lr;
#pragma unroll
            for (int r = 0; r < 4; ++r) {
                outp[(size_t)(i0 + r) * NL + l] = acc[f][g][r];
            }
        }
    }
}

// ---------------- Phase 2: fp64 combine + argmax (one wave per (b,i)) ----------------
__global__ __launch_bounds__(256)
void hd_phase2(const float* __restrict__ ws, float* __restrict__ out, int SS) {
    const int wid  = blockIdx.x * 4 + (threadIdx.x >> 6);   // (b,i) flat index
    const int lane = threadIdx.x & 63;                       // l
    const int b = wid >> 8, i = wid & 255;
    const float* p = ws + ((size_t)b * NI + i) * NL + lane;
    const size_t sstride = (size_t)B * NI * NL;              // 1,048,576

    double s0 = 0.0, s1 = 0.0, s2 = 0.0, s3 = 0.0;
    int ss = 0;
    for (; ss + 4 <= SS; ss += 4) {
        s0 += (double)p[(size_t)(ss + 0) * sstride];
        s1 += (double)p[(size_t)(ss + 1) * sstride];
        s2 += (double)p[(size_t)(ss + 2) * sstride];
        s3 += (double)p[(size_t)(ss + 3) * sstride];
    }
    for (; ss < SS; ++ss) s0 += (double)p[(size_t)ss * sstride];

    double mv = (s0 + s1) + (s2 + s3);
    int mi = lane;
#pragma unroll
    for (int off = 1; off < 64; off <<= 1) {
        double ov = __shfl_xor(mv, off);
        int   oi  = __shfl_xor(mi, off);
        if (ov > mv || (ov == mv && oi < mi)) { mv = ov; mi = oi; }  // first-index tie-break
    }
    if (lane == 0) out[wid] = (float)mi * BIN_LEN;
}

extern "C" void kernel_launch(void* const* d_in, const int* in_sizes, int n_in,
                              void* d_out, int out_size, void* d_ws, size_t ws_size,
                              hipStream_t stream) {
    const float* x       = (const float*)d_in[0];
    const float* id_hvs  = (const float*)d_in[1];
    const float* lvl_hvs = (const float*)d_in[2];
    float* out = (float*)d_out;

    // pick S (k-splits): need S*4MB partials + 10.3MB id arrays in ws
    int S = 16;
    while (S > 1 && ws_size < ((size_t)S << 22) + 2 * IDSZ * sizeof(_Float16)) S >>= 1;

    float*     part = (float*)d_ws;
    _Float16*  idh  = (_Float16*)((char*)d_ws + ((size_t)S << 22));
    _Float16*  idl  = idh + IDSZ;

    hd_split_id<<<dim3(NI), dim3(256), 0, stream>>>(id_hvs, idh, idl);
    // S*32 blocks: S x 32 b-pairs (S=16 -> 512 blocks = 2/CU, full residency)
    hd_mfma<<<dim3(S * 32), dim3(256), 0, stream>>>(x, lvl_hvs, idh, idl, part, S);
    hd_phase2<<<dim3(B * NI / 4), dim3(256), 0, stream>>>(part, out, S);
}

// Round 14
// 94.596 us; speedup vs baseline: 1.6432x; 1.2310x over previous
//
#include <hip/hip_runtime.h>

// hd_id_lvl_decoder: scores[b,i,l] = sum_d x[b,d]*id[i,d]*lvl[l,d]; out[b,i] = argmax_l * 0.015625
// B=64, NUM_ID=256, NUM_LVL=64, D=10000.
//
// f16x2-split MFMA, 3-term (hh + hl + lh; ll dropped ~6e-6, below fp32 noise).
// R14 = R7 (the proven 70 us optimum; R8-R13's six structural deviations all regressed)
// with ONE micro-change: COMPUTE's MFMA order is term-major within each f, so the two
// dependent accC MFMAs per (f,g) are separated by 3 independent MFMAs (ILP at 2 waves/SIMD).
// Register law (R7-R13): waves/SIMD = floor(512/(VGPR+AGPR)); dual acc = 128 AGPR + 128 VGPR
// = exactly 2 waves/SIMD. Any VGPR growth past 128 collapses to 1 wave -> keep staging lean.
// Phase 2: one wave per (b,i), lane = l: fp64 sum of S partials, shfl_xor argmax (first ties).

typedef _Float16 f16x8 __attribute__((ext_vector_type(8)));
typedef float f32x4 __attribute__((ext_vector_type(4)));

constexpr int D    = 10000;
constexpr int KPAD = 10016;            // 313 * 32
constexpr int B    = 64;
constexpr int NI   = 256;
constexpr int NL   = 64;
constexpr int BK   = 32;
constexpr int NCH  = KPAD / BK;        // 313 chunks
constexpr int S    = 8;                // k-splits
constexpr int BM   = 128;              // i per block
constexpr float BIN_LEN = 0.015625f;

// ws layout (bytes): [0, 32M) partials; then idh (256*10016 f16), idl.
constexpr size_t OFF_IDH = (size_t)S * B * NI * NL * 4;          // 33,554,432
constexpr size_t IDSZ    = (size_t)NI * KPAD;                     // elements per id array

__device__ __forceinline__ float4 ld4(const float* p) {
    return *reinterpret_cast<const float4*>(p);
}

// ---------------- Phase 0: split id into f16 hi/lo, zero-pad to KPAD ----------------
__global__ __launch_bounds__(256)
void hd_split_id(const float* __restrict__ id_hvs,
                 _Float16* __restrict__ idh, _Float16* __restrict__ idl) {
    const int i = blockIdx.x;          // 256 blocks, one i-row each
    for (int k = threadIdx.x; k < KPAD; k += 256) {
        float v = (k < D) ? id_hvs[(size_t)i * D + k] : 0.0f;
        _Float16 h = (_Float16)v;
        _Float16 lo = (_Float16)(v - (float)h);
        idh[(size_t)i * KPAD + k] = h;
        idl[(size_t)i * KPAD + k] = lo;
    }
}

// ---------------- Phase 1: MFMA main kernel ----------------
__global__ __launch_bounds__(256)
void hd_mfma(const float* __restrict__ x, const float* __restrict__ lvl_hvs,
             const _Float16* __restrict__ idh, const _Float16* __restrict__ idl,
             float* __restrict__ part) {
    // slot = kg ^ ((row>>1)&3) swizzle -> conflict-free (R6/R7 measured: 0)
    __shared__ f16x8 sA[2][2][BM][4];       // id tiles   [buf][hi/lo][row][slot], 32 KB
    __shared__ f16x8 sW[2][2][2][NL][4];    // w tiles    [buf][hi/lo][b][row][slot], 32 KB

    const int tid = threadIdx.x;
    const int bx  = blockIdx.x;
    const int s     = bx >> 6;          // 0..S-1
    const int ibase = (bx & 1) * BM;    // 0 or 128
    const int b0    = ((bx >> 1) & 31) * 2;

    // chunk range for this split
    const int cb = NCH / S, cr = NCH % S;          // 39, 1
    const int cstart = s * cb + (s < cr ? s : cr);
    const int nch    = cb + (s < cr ? 1 : 0);

    // w staging: thread -> lvl row (tid>>2)&63, kg tid&3
    const int w_row = (tid >> 2) & 63, w_kg = tid & 3;
    const int w_slot = w_kg ^ ((w_row >> 1) & 3);

    // wave / fragment decode: 4 waves as 2(i) x 2(b)
    const int wid = tid >> 6;
    const int wm = wid >> 1, wn = wid & 1;          // rows [wm*64,+64), b = b0+wn
    const int lr = tid & 15, lq = (tid >> 4) & 3;   // lane row/col sel, k-group

    f32x4 accM[4][4], accC[4][4];
#pragma unroll
    for (int f = 0; f < 4; ++f)
#pragma unroll
        for (int g = 0; g < 4; ++g) {
            accM[f][g] = (f32x4)0.0f;
            accC[f][g] = (f32x4)0.0f;
        }

    f16x8 r_id[4];
    float r_lv[8], r_x0[8], r_x1[8];

    auto LOAD_A = [&](int c) {
        const int k0 = (cstart + c) * BK;
#pragma unroll
        for (int m = 0; m < 4; ++m) {
            int u = tid + 256 * m;
            int arr = u >> 9, u2 = u & 511;
            int row = u2 >> 2, kg = u2 & 3;
            const _Float16* src = (arr ? idl : idh)
                + (size_t)(ibase + row) * KPAD + k0 + kg * 8;
            r_id[m] = *reinterpret_cast<const f16x8*>(src);
        }
    };

    auto WRITE_A = [&](int buf) {
#pragma unroll
        for (int m = 0; m < 4; ++m) {
            int u = tid + 256 * m;
            int arr = u >> 9, u2 = u & 511;
            int row = u2 >> 2, kg = u2 & 3;
            sA[buf][arr][row][kg ^ ((row >> 1) & 3)] = r_id[m];
        }
    };

    auto LOAD_W = [&](int c) {
        const int k0 = (cstart + c) * BK;
        const int kb = k0 + w_kg * 8;
        const float* lp  = lvl_hvs + (size_t)w_row * D + kb;
        const float* xp0 = x + (size_t)b0 * D + kb;
        const float* xp1 = xp0 + D;
        if (kb + 8 <= D) {
            float4 a0 = ld4(lp),  a1 = ld4(lp + 4);
            float4 c0 = ld4(xp0), c1 = ld4(xp0 + 4);
            float4 d0 = ld4(xp1), d1 = ld4(xp1 + 4);
            r_lv[0] = a0.x; r_lv[1] = a0.y; r_lv[2] = a0.z; r_lv[3] = a0.w;
            r_lv[4] = a1.x; r_lv[5] = a1.y; r_lv[6] = a1.z; r_lv[7] = a1.w;
            r_x0[0] = c0.x; r_x0[1] = c0.y; r_x0[2] = c0.z; r_x0[3] = c0.w;
            r_x0[4] = c1.x; r_x0[5] = c1.y; r_x0[6] = c1.z; r_x0[7] = c1.w;
            r_x1[0] = d0.x; r_x1[1] = d0.y; r_x1[2] = d0.z; r_x1[3] = d0.w;
            r_x1[4] = d1.x; r_x1[5] = d1.y; r_x1[6] = d1.z; r_x1[7] = d1.w;
        } else {
#pragma unroll
            for (int e = 0; e < 8; ++e) {
                bool in = (kb + e) < D;
                r_lv[e] = in ? lp[e]  : 0.0f;
                r_x0[e] = in ? xp0[e] : 0.0f;
                r_x1[e] = in ? xp1[e] : 0.0f;
            }
        }
    };

    auto WRITE_W = [&](int buf) {
#pragma unroll
        for (int bs = 0; bs < 2; ++bs) {
            const float* rx = bs ? r_x1 : r_x0;
            f16x8 h, lo;
#pragma unroll
            for (int e = 0; e < 8; ++e) {
                float w = rx[e] * r_lv[e];
                _Float16 hh = (_Float16)w;
                h[e] = hh;
                lo[e] = (_Float16)(w - (float)hh);
            }
            sW[buf][0][bs][w_row][w_slot] = h;
            sW[buf][1][bs][w_row][w_slot] = lo;
        }
    };

    auto COMPUTE = [&](int buf) {
        f16x8 bh[4], bl[4];
#pragma unroll
        for (int g = 0; g < 4; ++g) {
            int col = g * 16 + lr;
            int slot = lq ^ ((col >> 1) & 3);
            bh[g] = sW[buf][0][wn][col][slot];
            bl[g] = sW[buf][1][wn][col][slot];
        }
#pragma unroll
        for (int f = 0; f < 4; ++f) {
            int row = wm * 64 + f * 16 + lr;
            int slot = lq ^ ((row >> 1) & 3);
            f16x8 ah = sA[buf][0][row][slot];
            f16x8 al = sA[buf][1][row][slot];
            // term-major: each accC[g]'s two dependent MFMAs are separated by 3
            // independent ones (R7 issued them back-to-back -> dep stall at 2 waves/SIMD).
#pragma unroll
            for (int g = 0; g < 4; ++g)
                accM[f][g] = __builtin_amdgcn_mfma_f32_16x16x32_f16(ah, bh[g], accM[f][g], 0, 0, 0);
#pragma unroll
            for (int g = 0; g < 4; ++g)
                accC[f][g] = __builtin_amdgcn_mfma_f32_16x16x32_f16(ah, bl[g], accC[f][g], 0, 0, 0);
#pragma unroll
            for (int g = 0; g < 4; ++g)
                accC[f][g] = __builtin_amdgcn_mfma_f32_16x16x32_f16(al, bh[g], accC[f][g], 0, 0, 0);
        }
    };

    // prologue: chunk 0 staged
    LOAD_A(0);
    LOAD_W(0);
    WRITE_A(0);
    WRITE_W(0);
    __syncthreads();

    int cur = 0;
    for (int c = 0; c < nch; ++c) {
        const bool more = (c + 1 < nch);
        if (more) { LOAD_A(c + 1); LOAD_W(c + 1); }   // issue global loads early (T14)
        COMPUTE(cur);
        if (more) { WRITE_A(cur ^ 1); WRITE_W(cur ^ 1); }
        __syncthreads();
        cur ^= 1;
    }

    // epilogue: D layout col(lane&15)=l, row(lq*4+reg)=i offset. main + corr in fp32.
    float* outp = part + (size_t)(s * B + b0 + wn) * NI * NL;
#pragma unroll
    for (int f = 0; f < 4; ++f) {
#pragma unroll
        for (int g = 0; g < 4; ++g) {
            const int i0 = ibase + wm * 64 + f * 16 + lq * 4;
            const int l  = g * 16 + lr;
#pragma unroll
            for (int r = 0; r < 4; ++r) {
                outp[(size_t)(i0 + r) * NL + l] = accM[f][g][r] + accC[f][g][r];
            }
        }
    }
}

// ---------------- Phase 2: fp64 combine + argmax (one wave per (b,i)) ----------------
__global__ __launch_bounds__(256)
void hd_phase2(const float* __restrict__ ws, float* __restrict__ out, int SS) {
    const int wid  = blockIdx.x * 4 + (threadIdx.x >> 6);   // (b,i) flat index
    const int lane = threadIdx.x & 63;                       // l
    const int b = wid >> 8, i = wid & 255;
    const float* p = ws + ((size_t)b * NI + i) * NL + lane;
    const size_t sstride = (size_t)B * NI * NL;              // 1,048,576

    double s0 = 0.0, s1 = 0.0, s2 = 0.0, s3 = 0.0;
    int ss = 0;
    for (; ss + 4 <= SS; ss += 4) {
        s0 += (double)p[(size_t)(ss + 0) * sstride];
        s1 += (double)p[(size_t)(ss + 1) * sstride];
        s2 += (double)p[(size_t)(ss + 2) * sstride];
        s3 += (double)p[(size_t)(ss + 3) * sstride];
    }
    for (; ss < SS; ++ss) s0 += (double)p[(size_t)ss * sstride];

    double mv = (s0 + s1) + (s2 + s3);
    int mi = lane;
#pragma unroll
    for (int off = 1; off < 64; off <<= 1) {
        double ov = __shfl_xor(mv, off);
        int   oi  = __shfl_xor(mi, off);
        if (ov > mv || (ov == mv && oi < mi)) { mv = ov; mi = oi; }  // first-index tie-break
    }
    if (lane == 0) out[wid] = (float)mi * BIN_LEN;
}

extern "C" void kernel_launch(void* const* d_in, const int* in_sizes, int n_in,
                              void* d_out, int out_size, void* d_ws, size_t ws_size,
                              hipStream_t stream) {
    const float* x       = (const float*)d_in[0];
    const float* id_hvs  = (const float*)d_in[1];
    const float* lvl_hvs = (const float*)d_in[2];
    float* out = (float*)d_out;

    float*     part = (float*)d_ws;
    _Float16*  idh  = (_Float16*)((char*)d_ws + OFF_IDH);
    _Float16*  idl  = idh + IDSZ;

    hd_split_id<<<dim3(NI), dim3(256), 0, stream>>>(id_hvs, idh, idl);
    // 512 blocks: S x 32 b-pairs x 2 i-tiles
    hd_mfma<<<dim3(S * 64), dim3(256), 0, stream>>>(x, lvl_hvs, idh, idl, part);
    hd_phase2<<<dim3(B * NI / 4), dim3(256), 0, stream>>>(part, out, S);
}